// Round 20
// baseline (208.327 us; speedup 1.0000x reference)
//
#include <hip/hip_runtime.h>
#include <hip/hip_bf16.h>

typedef short s16;
typedef __attribute__((ext_vector_type(8))) short bf16x8;  // 8 bf16 = 4 VGPR (MFMA A/B frag)
typedef __attribute__((ext_vector_type(4))) float f32x4;   // MFMA C/D frag

// ---------------- helpers ----------------
__device__ __forceinline__ s16 f2bf(float f) {
  unsigned u = __builtin_bit_cast(unsigned, f);
  unsigned r = (u + 0x7FFFu + ((u >> 16) & 1u)) >> 16;
  return (s16)r;
}

__device__ __forceinline__ float hsig(float x) {
  return fminf(fmaxf(0.2f * x + 0.5f, 0.0f), 1.0f);
}

#define PXS 66
#define ROWSZ (PXS * 64)             // 4224 elements per tile row
#define ASZ4 (4 * ROWSZ)             // 4-row tile
#define ASZ6 (6 * ROWSZ)             // 6-row tile

// ---------------- prep kernel ----------------
// Weight layout per half-tap stage slice (16 KB = 8192 elems):
//   wq[stage u = tap*2+k][j][g][lane][8]
// lane = l4*16+l15, oc = j*64+g*16+l15, ic = k*32+l4*8+e.
__global__ void wprep_kernel(const float* __restrict__ rk0, const float* __restrict__ k1,
                             const float* __restrict__ rk1, const float* __restrict__ k0,
                             s16* __restrict__ w0q, s16* __restrict__ w1q,
                             s16* __restrict__ w2q, s16* __restrict__ k0t) {
  int idx = blockIdx.x * 256 + threadIdx.x;
  const int n1 = 18 * 8192;  // 147456
  if (idx < 3 * n1) {
    int which = idx / n1;
    int i = idx - which * n1;
    int e    = i & 7;
    int lane = (i >> 3) & 63;
    int g    = (i >> 9) & 3;
    int j    = (i >> 11) & 3;
    int k    = (i >> 13) & 1;
    int tap  = i >> 14;
    int l15 = lane & 15, l4 = lane >> 4;
    int ic = k * 32 + l4 * 8 + e;
    int oc = j * 64 + g * 16 + l15;
    const float* src = (which == 0) ? rk0 : (which == 1) ? k1 : rk1;
    s16* dst = (which == 0) ? w0q : (which == 1) ? w1q : w2q;
    dst[i] = f2bf(src[(tap * 64 + ic) * 256 + oc]);
  } else if (idx < 3 * n1 + 8192) {
    int r = idx - 3 * n1;
    int kk = r & 31;
    int oc = r >> 5;
    k0t[r] = (kk < 9) ? f2bf(k0[kk * 256 + oc]) : (s16)0;
  }
}

// ---------------- staging ----------------
template <bool F32>
__device__ __forceinline__ bf16x8 load_conv8(const void* src, long off) {
  if constexpr (F32) {
    const float* p = (const float*)src + off;
    float4 v0 = *reinterpret_cast<const float4*>(p);
    float4 v1 = *reinterpret_cast<const float4*>(p + 4);
    bf16x8 r;
    r[0] = f2bf(v0.x); r[1] = f2bf(v0.y); r[2] = f2bf(v0.z); r[3] = f2bf(v0.w);
    r[4] = f2bf(v1.x); r[5] = f2bf(v1.y); r[6] = f2bf(v1.z); r[7] = f2bf(v1.w);
    return r;
  } else {
    return *reinterpret_cast<const bf16x8*>((const s16*)src + off);
  }
}

// ROWS-row tile staged by NT threads
template <bool F32, int ROWS, int NT>
__device__ __forceinline__ void stageA(s16* a_lds, const void* src, int b, int y0, int tid) {
  #pragma unroll
  for (int i = 0; i < ROWS * 512 / NT; ++i) {
    int c   = tid + i * NT;         // 16B-chunks
    int row = c >> 9;
    int px  = (c >> 3) & 63;
    int cb  = c & 7;
    int y   = y0 - 1 + row;
    int xp  = px + 1;
    bf16x8 v = {};
    if ((unsigned)y < 64u)
      v = load_conv8<F32>(src, ((long)(b * 64 + y) * 64 + px) * 64 + cb * 8);
    *reinterpret_cast<bf16x8*>(a_lds + (row * PXS + xp) * 64 + ((cb ^ (xp & 7)) * 8)) = v;
  }
  if (tid < ROWS * 16) {  // zero x-border columns (xp = 0, 65)
    int row = tid >> 4;
    int xp  = ((tid >> 3) & 1) ? 65 : 0;
    int cb  = tid & 7;
    bf16x8 z = {};
    *reinterpret_cast<bf16x8*>(a_lds + (row * PXS + xp) * 64 + cb * 8) = z;
  }
}

// ---------------- LAYER 0 cell (R15 structure verbatim -- measured best, ~42us) ----------------
__global__ __launch_bounds__(1024, 1) void cell0_kernel(
    const float* __restrict__ h0,   // fp32
    const s16* __restrict__ w0,     // wq [18][8192]
    const float* __restrict__ xin,
    const s16* __restrict__ k0t,
    const float* __restrict__ bias,
    const float* __restrict__ c_old,
    float* __restrict__ h_out,
    float* __restrict__ c_out,
    s16* __restrict__ hb_out)
{
  __shared__ __align__(16) s16 a_lds[ASZ6];
  __shared__ __align__(16) s16 w_lds[3][8192];
  __shared__ float x_lds[384];

  const int tid = threadIdx.x;
  const int b  = blockIdx.x >> 4;
  const int y0 = (blockIdx.x & 15) << 2;

  const int wave = tid >> 6;
  const int lane = tid & 63;
  const int g    = wave & 3;
  const int mh   = wave >> 2;
  const int l15  = lane & 15;
  const int l4   = lane >> 4;

  constexpr int NST = 18;

  auto issueW = [&](int u) {
    int v = (u >= NST) ? u - NST : u;
    const s16* wt = w0 + v * 8192;
    char* base = (char*)(&w_lds[0][0]) + (v % 3) * 16384 + (tid >> 6) * 1024;
    __builtin_amdgcn_global_load_lds(
        (const __attribute__((address_space(1))) void*)(wt + tid * 8),
        (__attribute__((address_space(3))) void*)base, 16, 0, 0);
  };
  auto readWf = [&](bf16x8 (&wf)[4], int slot) {
    const s16* wb = &w_lds[slot][0] + g * 512 + lane * 8;
    #pragma unroll
    for (int j = 0; j < 4; ++j)
      wf[j] = *reinterpret_cast<const bf16x8*>(wb + j * 2048);
  };

  f32x4 acc[4][4] = {};

  auto doStage = [&](const bf16x8 (&wf)[4], int u) {
    int tap = u >> 1, kk = u & 1;
    int dy = tap / 3, dx = tap - dy * 3;
    const char* sb = (const char*)a_lds + (mh + dy) * (ROWSZ * 2);
    bf16x8 af[4];
    #pragma unroll
    for (int m = 0; m < 4; ++m) {
      int xq   = m * 16 + l15 + dx;
      int boff = xq * 128 + ((((kk << 2) | l4) ^ (xq & 7)) << 4);
      af[m] = *reinterpret_cast<const bf16x8*>(sb + boff);
    }
    __builtin_amdgcn_s_setprio(1);
    #pragma unroll
    for (int m = 0; m < 4; ++m) {
      #pragma unroll
      for (int j = 0; j < 4; ++j)
        acc[m][j] = __builtin_amdgcn_mfma_f32_16x16x32_bf16(af[m], wf[j], acc[m][j], 0, 0, 0);
    }
    __builtin_amdgcn_s_setprio(0);
  };

  issueW(0);
  issueW(1);
  stageA<true, 6, 1024>(a_lds, h0, b, y0, tid);
  if (tid < 384) {
    int row = tid >> 6, px = tid & 63;
    int y = y0 - 1 + row;
    x_lds[tid] = ((unsigned)y < 64u) ? xin[(b * 64 + y) * 64 + px] : 0.0f;
  }
  __syncthreads();

  {
    bf16x8 bx[4];
    #pragma unroll
    for (int j = 0; j < 4; ++j) {
      int oc = j * 64 + g * 16 + l15;
      bx[j] = *reinterpret_cast<const bf16x8*>(k0t + oc * 32 + l4 * 8);
    }
    #pragma unroll
    for (int m = 0; m < 4; ++m) {
      int px = m * 16 + l15;
      bf16x8 ax = {};
      #pragma unroll
      for (int e = 0; e < 8; ++e) {
        int t = l4 * 8 + e;
        if (t < 9) {
          int dyt = t / 3, dxt = t - dyt * 3;
          int xx = px + dxt - 1;
          float xv = ((unsigned)xx < 64u) ? x_lds[(mh + dyt) * 64 + xx] : 0.0f;
          ax[e] = f2bf(xv);
        }
      }
      #pragma unroll
      for (int j = 0; j < 4; ++j)
        acc[m][j] = __builtin_amdgcn_mfma_f32_16x16x32_bf16(ax, bx[j], acc[m][j], 0, 0, 0);
    }
  }

  bf16x8 wf[4];
  #pragma unroll
  for (int u = 0; u < NST; ++u) {
    asm volatile("s_waitcnt vmcnt(1)" ::: "memory");
    __builtin_amdgcn_s_barrier();
    __builtin_amdgcn_sched_barrier(0);
    issueW(u + 2);
    readWf(wf, u % 3);
    doStage(wf, u);
  }

  float bi[4];
  #pragma unroll
  for (int j = 0; j < 4; ++j) bi[j] = bias[j * 64 + g * 16 + l15];
  const int pix_base = b * 4096 + y0 * 64;
  const int f = g * 16 + l15;
  #pragma unroll
  for (int m = 0; m < 4; ++m) {
    #pragma unroll
    for (int r = 0; r < 4; ++r) {
      int pl = mh * 64 + m * 16 + l4 * 4 + r;
      int off = (pix_base + pl) * 64 + f;
      float zi = acc[m][0][r] + bi[0];
      float zf = acc[m][1][r] + bi[1];
      float zc = acc[m][2][r] + bi[2];
      float zo = acc[m][3][r] + bi[3];
      float ig = hsig(zi), fg = hsig(zf), og = hsig(zo);
      float cn = fg * c_old[off] + ig * tanhf(zc);
      float hn = og * tanhf(cn);
      c_out[off] = cn;
      h_out[off] = hn;
      hb_out[off] = f2bf(hn);
    }
  }
}

// ---------------- LAYER 1 cell: W-IN-REGISTERS (probe structure made real) ----------------
// Block: 512 threads = 8 waves, 1 block/CU (235 regs -> 2 waves/SIMD).
// Tile: M=128 px (2 output rows), N=256. Wave w = (fh = w>>2 : feature-half,
// j = w&3 : gate): oc range = j*64 + fh*32 + [0,32). Whole per-source W working
// set = 18 stages x 2 frags = 144 VGPR, loaded ONCE per source pass -> the
// K-loop is pure {ds_read A + MFMA}, barrier-free (the R11 probe structure that
// measured 46us vs 133 with any per-stage W stream). Epilogue: z exchanged via
// LDS (reusing the A tile, [64 px][260] fp32-padded) in 2 half-rounds, then
// pointwise LSTM with all gates lane-local.
// grid: 1024 blocks: b = blk>>5, y0 = (blk&31)*2.
#define ZP 260   // z row stride in floats (padded; 64*260*4 = 66.6KB <= 67.6KB)
__global__ __launch_bounds__(512, 2) void cell1_kernel(
    const s16* __restrict__ src0,   // h0nb bf16
    const float* __restrict__ src1, // h1 fp32
    const s16* __restrict__ w0,     // k1 wq
    const s16* __restrict__ w1,     // rk1 wq
    const float* __restrict__ bias,
    const float* __restrict__ c_old,
    float* __restrict__ h_out,
    float* __restrict__ c_out)
{
  __shared__ __align__(16) s16 a_lds[2 * ASZ4];   // 67.6 KB; reused as z after K-loop

  const int tid = threadIdx.x;
  const int b  = blockIdx.x >> 5;
  const int y0 = (blockIdx.x & 31) << 1;

  const int wave = tid >> 6;
  const int lane = tid & 63;
  const int j    = wave & 3;    // gate
  const int fh   = wave >> 2;   // 0..1: feature half
  const int l15  = lane & 15;
  const int l4   = lane >> 4;

  // ---- W register file (pass 0: k1). Issue before staging so latency overlaps. ----
  bf16x8 wreg[18][2];
  {
    const s16* wb = w0 + j * 2048 + fh * 1024 + lane * 8;
    #pragma unroll
    for (int u = 0; u < 18; ++u) {
      wreg[u][0] = *reinterpret_cast<const bf16x8*>(wb + u * 8192);
      wreg[u][1] = *reinterpret_cast<const bf16x8*>(wb + u * 8192 + 512);
    }
  }

  stageA<false, 4, 512>(a_lds, src0, b, y0, tid);
  stageA<true, 4, 512>(a_lds + ASZ4, src1, b, y0, tid);
  __syncthreads();

  f32x4 acc[8][2] = {};  // [m-frag: (m>>2)=row, (m&3)=x-quarter][oc-frag q]

  // ---- pass 0: src0 x k1, barrier-free, W from registers ----
  #pragma unroll
  for (int u = 0; u < 18; ++u) {
    int tap = u >> 1, kk = u & 1;
    int dy = tap / 3, dx = tap - dy * 3;
    #pragma unroll
    for (int m = 0; m < 8; ++m) {
      int row  = (m >> 2) + dy;
      int xq   = (m & 3) * 16 + l15 + dx;
      int boff = xq * 128 + ((((kk << 2) | l4) ^ (xq & 7)) << 4);
      bf16x8 a = *reinterpret_cast<const bf16x8*>((const char*)a_lds + row * (ROWSZ * 2) + boff);
      acc[m][0] = __builtin_amdgcn_mfma_f32_16x16x32_bf16(a, wreg[u][0], acc[m][0], 0, 0, 0);
      acc[m][1] = __builtin_amdgcn_mfma_f32_16x16x32_bf16(a, wreg[u][1], acc[m][1], 0, 0, 0);
    }
  }

  // ---- reload W registers (pass 1: rk1) ----
  {
    const s16* wb = w1 + j * 2048 + fh * 1024 + lane * 8;
    #pragma unroll
    for (int u = 0; u < 18; ++u) {
      wreg[u][0] = *reinterpret_cast<const bf16x8*>(wb + u * 8192);
      wreg[u][1] = *reinterpret_cast<const bf16x8*>(wb + u * 8192 + 512);
    }
  }

  // ---- pass 1: src1 x rk1 ----
  #pragma unroll
  for (int u = 0; u < 18; ++u) {
    int tap = u >> 1, kk = u & 1;
    int dy = tap / 3, dx = tap - dy * 3;
    #pragma unroll
    for (int m = 0; m < 8; ++m) {
      int row  = (m >> 2) + dy;
      int xq   = (m & 3) * 16 + l15 + dx;
      int boff = xq * 128 + ((((kk << 2) | l4) ^ (xq & 7)) << 4);
      bf16x8 a = *reinterpret_cast<const bf16x8*>((const char*)a_lds + ASZ4 * 2 + row * (ROWSZ * 2) + boff);
      acc[m][0] = __builtin_amdgcn_mfma_f32_16x16x32_bf16(a, wreg[u][0], acc[m][0], 0, 0, 0);
      acc[m][1] = __builtin_amdgcn_mfma_f32_16x16x32_bf16(a, wreg[u][1], acc[m][1], 0, 0, 0);
    }
  }

  // ---- epilogue: 2 half-rounds of z-exchange through LDS, then pointwise LSTM ----
  float* z_lds = (float*)a_lds;   // [64 px][ZP] floats
  const int pix_base = b * 4096 + y0 * 64;
  #pragma unroll
  for (int h = 0; h < 2; ++h) {
    __syncthreads();   // K-loop A-reads (h=0) / previous half's z-reads (h=1) done
    // write phase: this wave's z for output row h (m in [h*4, h*4+4))
    #pragma unroll
    for (int mm = 0; mm < 4; ++mm) {
      #pragma unroll
      for (int q = 0; q < 2; ++q) {
        int oc = j * 64 + fh * 32 + q * 16 + l15;
        #pragma unroll
        for (int r = 0; r < 4; ++r) {
          int px = mm * 16 + l4 * 4 + r;   // 0..63 within the row
          z_lds[px * ZP + oc] = acc[h * 4 + mm][q][r];
        }
      }
    }
    __syncthreads();
    // finish phase: lane handles px8 = wave*8 + (lane>>3), f0 = (lane&7)*8
    int px8 = wave * 8 + (lane >> 3);
    int f0  = (lane & 7) * 8;
    const float* zr = z_lds + px8 * ZP;
    int off0 = (pix_base + h * 64 + px8) * 64 + f0;
    #pragma unroll
    for (int half8 = 0; half8 < 2; ++half8) {  // two float4 chunks of the 8 f's
      float4 zi4 = *reinterpret_cast<const float4*>(zr + f0 + half8 * 4);
      float4 zf4 = *reinterpret_cast<const float4*>(zr + 64 + f0 + half8 * 4);
      float4 zc4 = *reinterpret_cast<const float4*>(zr + 128 + f0 + half8 * 4);
      float4 zo4 = *reinterpret_cast<const float4*>(zr + 192 + f0 + half8 * 4);
      float4 bi4 = *reinterpret_cast<const float4*>(bias + f0 + half8 * 4);
      float4 bf4 = *reinterpret_cast<const float4*>(bias + 64 + f0 + half8 * 4);
      float4 bc4 = *reinterpret_cast<const float4*>(bias + 128 + f0 + half8 * 4);
      float4 bo4 = *reinterpret_cast<const float4*>(bias + 192 + f0 + half8 * 4);
      float4 co4 = *reinterpret_cast<const float4*>(c_old + off0 + half8 * 4);
      float4 hn4, cn4;
      #pragma unroll
      for (int e = 0; e < 4; ++e) {
        float zi = (&zi4.x)[e] + (&bi4.x)[e];
        float zf = (&zf4.x)[e] + (&bf4.x)[e];
        float zc = (&zc4.x)[e] + (&bc4.x)[e];
        float zo = (&zo4.x)[e] + (&bo4.x)[e];
        float ig = hsig(zi), fg = hsig(zf), og = hsig(zo);
        float cn = fg * (&co4.x)[e] + ig * tanhf(zc);
        (&cn4.x)[e] = cn;
        (&hn4.x)[e] = og * tanhf(cn);
      }
      *reinterpret_cast<float4*>(c_out + off0 + half8 * 4) = cn4;
      *reinterpret_cast<float4*>(h_out + off0 + half8 * 4) = hn4;
    }
  }
}

// ---------------- 1x1 conv head ----------------
__global__ void frames_kernel(const float* __restrict__ h, const float* __restrict__ cw,
                              const float* __restrict__ cbp, float* __restrict__ out) {
  int tid = blockIdx.x * 256 + threadIdx.x;
  int p  = tid >> 2;
  int fc = (tid & 3) * 16;
  const float4* hp = reinterpret_cast<const float4*>(h + p * 64 + fc);
  const float4* wp = reinterpret_cast<const float4*>(cw + fc);
  float s = 0.0f;
  #pragma unroll
  for (int i = 0; i < 4; ++i) {
    float4 v = hp[i];
    float4 w = wp[i];
    s += v.x * w.x + v.y * w.y + v.z * w.z + v.w * w.w;
  }
  s += __shfl_xor(s, 1);
  s += __shfl_xor(s, 2);
  if ((tid & 3) == 0) out[p] = s + cbp[0];
}

// ---------------- launch ----------------
extern "C" void kernel_launch(void* const* d_in, const int* in_sizes, int n_in,
                              void* d_out, int out_size, void* d_ws, size_t ws_size,
                              hipStream_t stream) {
  const float* x   = (const float*)d_in[0];
  const float* h0  = (const float*)d_in[1];
  const float* c0  = (const float*)d_in[2];
  const float* h1  = (const float*)d_in[3];
  const float* c1  = (const float*)d_in[4];
  const float* k0  = (const float*)d_in[5];
  const float* rk0 = (const float*)d_in[6];
  const float* b0  = (const float*)d_in[7];
  const float* k1  = (const float*)d_in[8];
  const float* rk1 = (const float*)d_in[9];
  const float* b1  = (const float*)d_in[10];
  const float* cw  = (const float*)d_in[11];
  const float* cbp = (const float*)d_in[12];

  float* out    = (float*)d_out;
  float* frames = out;                       // [32,64,64,1]
  float* h0n    = out + 131072;              // [32,64,64,64]
  float* c0n    = out + 131072 + 8388608;
  float* h1n    = out + 131072 + 2 * 8388608;
  float* c1n    = out + 131072 + 3 * 8388608;

  char* ws = (char*)d_ws;
  const size_t SZ_H = 16777216;  // bytes per bf16 [32,64,64,64] buffer
  s16* h0nb = (s16*)(ws + 0 * SZ_H);
  s16* w0q  = (s16*)(ws + 1 * SZ_H);                 // rk0 shuffled
  s16* w1q  = (s16*)(ws + 1 * SZ_H + 1 * 294912);    // k1 shuffled
  s16* w2q  = (s16*)(ws + 1 * SZ_H + 2 * 294912);    // rk1 shuffled
  s16* k0t  = (s16*)(ws + 1 * SZ_H + 3 * 294912);    // k0 padded [256][32]

  // prep (single launch)
  wprep_kernel<<<1760, 256, 0, stream>>>(rk0, k1, rk1, k0, w0q, w1q, w2q, k0t);

  // layer 0 (R15 structure: measured best L0, ~42 us)
  cell0_kernel<<<512, 1024, 0, stream>>>(
      h0, w0q, x, k0t, b0, c0, h0n, c0n, h0nb);

  // layer 1 (W-in-registers probe structure)
  cell1_kernel<<<1024, 512, 0, stream>>>(
      h0nb, h1, w1q, w2q, b1, c1, h1n, c1n);

  // head
  frames_kernel<<<2048, 256, 0, stream>>>(h1n, cw, cbp, frames);
}

// Round 21
// 180.996 us; speedup vs baseline: 1.1510x; 1.1510x over previous
//
#include <hip/hip_runtime.h>
#include <hip/hip_bf16.h>

typedef short s16;
typedef __attribute__((ext_vector_type(8))) short bf16x8;  // 8 bf16 = 4 VGPR (MFMA A/B frag)
typedef __attribute__((ext_vector_type(4))) float f32x4;   // MFMA C/D frag

// ---------------- helpers ----------------
__device__ __forceinline__ s16 f2bf(float f) {
  unsigned u = __builtin_bit_cast(unsigned, f);
  unsigned r = (u + 0x7FFFu + ((u >> 16) & 1u)) >> 16;
  return (s16)r;
}

__device__ __forceinline__ float hsig(float x) {
  return fminf(fmaxf(0.2f * x + 0.5f, 0.0f), 1.0f);
}

#define PXS 66
#define ROWSZ (PXS * 64)             // 4224 elements per tile row
#define ASZ4 (4 * ROWSZ)             // 4-row tile
#define ASZ6 (6 * ROWSZ)             // 6-row tile

// ---------------- prep kernel ----------------
// Weight layout per half-tap stage slice (16 KB = 8192 elems):
//   wq[stage u = tap*2+k][j][g][lane][8]
// lane = l4*16+l15, oc = j*64+g*16+l15, ic = k*32+l4*8+e.
__global__ void wprep_kernel(const float* __restrict__ rk0, const float* __restrict__ k1,
                             const float* __restrict__ rk1, const float* __restrict__ k0,
                             s16* __restrict__ w0q, s16* __restrict__ w1q,
                             s16* __restrict__ w2q, s16* __restrict__ k0t) {
  int idx = blockIdx.x * 256 + threadIdx.x;
  const int n1 = 18 * 8192;  // 147456
  if (idx < 3 * n1) {
    int which = idx / n1;
    int i = idx - which * n1;
    int e    = i & 7;
    int lane = (i >> 3) & 63;
    int g    = (i >> 9) & 3;
    int j    = (i >> 11) & 3;
    int k    = (i >> 13) & 1;
    int tap  = i >> 14;
    int l15 = lane & 15, l4 = lane >> 4;
    int ic = k * 32 + l4 * 8 + e;
    int oc = j * 64 + g * 16 + l15;
    const float* src = (which == 0) ? rk0 : (which == 1) ? k1 : rk1;
    s16* dst = (which == 0) ? w0q : (which == 1) ? w1q : w2q;
    dst[i] = f2bf(src[(tap * 64 + ic) * 256 + oc]);
  } else if (idx < 3 * n1 + 8192) {
    int r = idx - 3 * n1;
    int kk = r & 31;
    int oc = r >> 5;
    k0t[r] = (kk < 9) ? f2bf(k0[kk * 256 + oc]) : (s16)0;
  }
}

// ---------------- staging ----------------
template <bool F32>
__device__ __forceinline__ bf16x8 load_conv8(const void* src, long off) {
  if constexpr (F32) {
    const float* p = (const float*)src + off;
    float4 v0 = *reinterpret_cast<const float4*>(p);
    float4 v1 = *reinterpret_cast<const float4*>(p + 4);
    bf16x8 r;
    r[0] = f2bf(v0.x); r[1] = f2bf(v0.y); r[2] = f2bf(v0.z); r[3] = f2bf(v0.w);
    r[4] = f2bf(v1.x); r[5] = f2bf(v1.y); r[6] = f2bf(v1.z); r[7] = f2bf(v1.w);
    return r;
  } else {
    return *reinterpret_cast<const bf16x8*>((const s16*)src + off);
  }
}

// ROWS-row tile staged by NT threads
template <bool F32, int ROWS, int NT>
__device__ __forceinline__ void stageA(s16* a_lds, const void* src, int b, int y0, int tid) {
  #pragma unroll
  for (int i = 0; i < ROWS * 512 / NT; ++i) {
    int c   = tid + i * NT;         // 16B-chunks
    int row = c >> 9;
    int px  = (c >> 3) & 63;
    int cb  = c & 7;
    int y   = y0 - 1 + row;
    int xp  = px + 1;
    bf16x8 v = {};
    if ((unsigned)y < 64u)
      v = load_conv8<F32>(src, ((long)(b * 64 + y) * 64 + px) * 64 + cb * 8);
    *reinterpret_cast<bf16x8*>(a_lds + (row * PXS + xp) * 64 + ((cb ^ (xp & 7)) * 8)) = v;
  }
  if (tid < ROWS * 16) {  // zero x-border columns (xp = 0, 65)
    int row = tid >> 4;
    int xp  = ((tid >> 3) & 1) ? 65 : 0;
    int cb  = tid & 7;
    bf16x8 z = {};
    *reinterpret_cast<bf16x8*>(a_lds + (row * PXS + xp) * 64 + cb * 8) = z;
  }
}

// ---------------- LAYER 0 cell (R15 structure verbatim -- measured best, ~42us) ----------------
__global__ __launch_bounds__(1024, 1) void cell0_kernel(
    const float* __restrict__ h0,   // fp32
    const s16* __restrict__ w0,     // wq [18][8192]
    const float* __restrict__ xin,
    const s16* __restrict__ k0t,
    const float* __restrict__ bias,
    const float* __restrict__ c_old,
    float* __restrict__ h_out,
    float* __restrict__ c_out,
    s16* __restrict__ hb_out)
{
  __shared__ __align__(16) s16 a_lds[ASZ6];
  __shared__ __align__(16) s16 w_lds[3][8192];
  __shared__ float x_lds[384];

  const int tid = threadIdx.x;
  const int b  = blockIdx.x >> 4;
  const int y0 = (blockIdx.x & 15) << 2;

  const int wave = tid >> 6;
  const int lane = tid & 63;
  const int g    = wave & 3;
  const int mh   = wave >> 2;
  const int l15  = lane & 15;
  const int l4   = lane >> 4;

  constexpr int NST = 18;

  auto issueW = [&](int u) {
    int v = (u >= NST) ? u - NST : u;
    const s16* wt = w0 + v * 8192;
    char* base = (char*)(&w_lds[0][0]) + (v % 3) * 16384 + (tid >> 6) * 1024;
    __builtin_amdgcn_global_load_lds(
        (const __attribute__((address_space(1))) void*)(wt + tid * 8),
        (__attribute__((address_space(3))) void*)base, 16, 0, 0);
  };
  auto readWf = [&](bf16x8 (&wf)[4], int slot) {
    const s16* wb = &w_lds[slot][0] + g * 512 + lane * 8;
    #pragma unroll
    for (int j = 0; j < 4; ++j)
      wf[j] = *reinterpret_cast<const bf16x8*>(wb + j * 2048);
  };

  f32x4 acc[4][4] = {};

  auto doStage = [&](const bf16x8 (&wf)[4], int u) {
    int tap = u >> 1, kk = u & 1;
    int dy = tap / 3, dx = tap - dy * 3;
    const char* sb = (const char*)a_lds + (mh + dy) * (ROWSZ * 2);
    bf16x8 af[4];
    #pragma unroll
    for (int m = 0; m < 4; ++m) {
      int xq   = m * 16 + l15 + dx;
      int boff = xq * 128 + ((((kk << 2) | l4) ^ (xq & 7)) << 4);
      af[m] = *reinterpret_cast<const bf16x8*>(sb + boff);
    }
    __builtin_amdgcn_s_setprio(1);
    #pragma unroll
    for (int m = 0; m < 4; ++m) {
      #pragma unroll
      for (int j = 0; j < 4; ++j)
        acc[m][j] = __builtin_amdgcn_mfma_f32_16x16x32_bf16(af[m], wf[j], acc[m][j], 0, 0, 0);
    }
    __builtin_amdgcn_s_setprio(0);
  };

  issueW(0);
  issueW(1);
  stageA<true, 6, 1024>(a_lds, h0, b, y0, tid);
  if (tid < 384) {
    int row = tid >> 6, px = tid & 63;
    int y = y0 - 1 + row;
    x_lds[tid] = ((unsigned)y < 64u) ? xin[(b * 64 + y) * 64 + px] : 0.0f;
  }
  __syncthreads();

  {
    bf16x8 bx[4];
    #pragma unroll
    for (int j = 0; j < 4; ++j) {
      int oc = j * 64 + g * 16 + l15;
      bx[j] = *reinterpret_cast<const bf16x8*>(k0t + oc * 32 + l4 * 8);
    }
    #pragma unroll
    for (int m = 0; m < 4; ++m) {
      int px = m * 16 + l15;
      bf16x8 ax = {};
      #pragma unroll
      for (int e = 0; e < 8; ++e) {
        int t = l4 * 8 + e;
        if (t < 9) {
          int dyt = t / 3, dxt = t - dyt * 3;
          int xx = px + dxt - 1;
          float xv = ((unsigned)xx < 64u) ? x_lds[(mh + dyt) * 64 + xx] : 0.0f;
          ax[e] = f2bf(xv);
        }
      }
      #pragma unroll
      for (int j = 0; j < 4; ++j)
        acc[m][j] = __builtin_amdgcn_mfma_f32_16x16x32_bf16(ax, bx[j], acc[m][j], 0, 0, 0);
    }
  }

  bf16x8 wf[4];
  #pragma unroll
  for (int u = 0; u < NST; ++u) {
    asm volatile("s_waitcnt vmcnt(1)" ::: "memory");
    __builtin_amdgcn_s_barrier();
    __builtin_amdgcn_sched_barrier(0);
    issueW(u + 2);
    readWf(wf, u % 3);
    doStage(wf, u);
  }

  float bi[4];
  #pragma unroll
  for (int j = 0; j < 4; ++j) bi[j] = bias[j * 64 + g * 16 + l15];
  const int pix_base = b * 4096 + y0 * 64;
  const int f = g * 16 + l15;
  #pragma unroll
  for (int m = 0; m < 4; ++m) {
    #pragma unroll
    for (int r = 0; r < 4; ++r) {
      int pl = mh * 64 + m * 16 + l4 * 4 + r;
      int off = (pix_base + pl) * 64 + f;
      float zi = acc[m][0][r] + bi[0];
      float zf = acc[m][1][r] + bi[1];
      float zc = acc[m][2][r] + bi[2];
      float zo = acc[m][3][r] + bi[3];
      float ig = hsig(zi), fg = hsig(zf), og = hsig(zo);
      float cn = fg * c_old[off] + ig * tanhf(zc);
      float hn = og * tanhf(cn);
      c_out[off] = cn;
      h_out[off] = hn;
      hb_out[off] = f2bf(hn);
    }
  }
}

// ---------------- LAYER 1 cell: W-in-registers, quarter-pass reloads ----------------
// Block: 1024 threads = 16 waves, 1 block/CU, 4 waves/SIMD (<=128 regs/wave).
// Tile: M=128 px (2 output rows), N=256. Wave (mh = wave>>3 : output row,
// s8 = wave&7 : 32-oc slice; j = s8>>1 gate-pair base, g0 = (s8&1)*2).
// K region: 4 quarter-passes {src0/k-half0, src0/k-half1, src1/kh0, src1/kh1};
// each reloads wreg[9][2] (72 VGPR, wave-private, 18 pipelined global loads)
// then runs 9 tap-stages of pure {4 ds_read A -> 8 MFMA} -- BARRIER-FREE
// (the R11 probe structure: 46us). acc[4][2] = 32 regs. Total ~124 regs.
// Epilogue: z-exchange via LDS (reuse A tile as [64px][ZP] fp32), 2 half-rounds.
// grid: 1024 blocks: b = blk>>5, y0 = (blk&31)*2.
#define ZP 260
__global__ __launch_bounds__(1024, 4) void cell1_kernel(
    const s16* __restrict__ src0,   // h0nb bf16
    const float* __restrict__ src1, // h1 fp32
    const s16* __restrict__ w0,     // k1 wq
    const s16* __restrict__ w1,     // rk1 wq
    const float* __restrict__ bias,
    const float* __restrict__ c_old,
    float* __restrict__ h_out,
    float* __restrict__ c_out)
{
  __shared__ __align__(16) s16 a_lds[2 * ASZ4];   // 67.6 KB; reused as z after K

  const int tid = threadIdx.x;
  const int b  = blockIdx.x >> 5;
  const int y0 = (blockIdx.x & 31) << 1;

  const int wave = tid >> 6;
  const int lane = tid & 63;
  const int mh   = wave >> 3;      // 0..1: output row
  const int s8   = wave & 7;       // 32-oc slice
  const int jj   = s8 >> 1;
  const int g0   = (s8 & 1) * 2;
  const int l15  = lane & 15;
  const int l4   = lane >> 4;

  stageA<false, 4, 1024>(a_lds, src0, b, y0, tid);
  stageA<true, 4, 1024>(a_lds + ASZ4, src1, b, y0, tid);
  __syncthreads();

  f32x4 acc[4][2] = {};  // [m x-quarter][oc-frag q] -- 32 regs
  const int wloff = jj * 2048 + g0 * 512 + lane * 8;

  auto qpass = [&](const s16* wsrc, const char* abase, int kk) {
    // reload this quarter's W working set (wave-private, 18 pipelined loads)
    bf16x8 wreg[9][2];
    #pragma unroll
    for (int t = 0; t < 9; ++t) {
      const s16* wp = wsrc + (t * 2 + kk) * 8192 + wloff;
      wreg[t][0] = *reinterpret_cast<const bf16x8*>(wp);
      wreg[t][1] = *reinterpret_cast<const bf16x8*>(wp + 512);
    }
    // 9 tap-stages: pure ds_read A + MFMA, no barriers, no vmcnt
    #pragma unroll
    for (int t = 0; t < 9; ++t) {
      int dy = t / 3, dx = t - dy * 3;
      const char* sb = abase + (mh + dy) * (ROWSZ * 2);
      #pragma unroll
      for (int m = 0; m < 4; ++m) {
        int xq   = m * 16 + l15 + dx;
        int boff = xq * 128 + ((((kk << 2) | l4) ^ (xq & 7)) << 4);
        bf16x8 a = *reinterpret_cast<const bf16x8*>(sb + boff);
        acc[m][0] = __builtin_amdgcn_mfma_f32_16x16x32_bf16(a, wreg[t][0], acc[m][0], 0, 0, 0);
        acc[m][1] = __builtin_amdgcn_mfma_f32_16x16x32_bf16(a, wreg[t][1], acc[m][1], 0, 0, 0);
      }
    }
  };

  qpass(w0, (const char*)a_lds, 0);
  qpass(w0, (const char*)a_lds, 1);
  qpass(w1, (const char*)a_lds + ASZ4 * 2, 0);
  qpass(w1, (const char*)a_lds + ASZ4 * 2, 1);

  // ---- epilogue: z-exchange through LDS, 2 half-rounds, pointwise LSTM ----
  float* z_lds = (float*)a_lds;   // [64 px][ZP] floats (66.6 KB)
  const int pix_base = b * 4096 + y0 * 64;
  #pragma unroll
  for (int h = 0; h < 2; ++h) {
    __syncthreads();   // K-loop A-reads (h=0) / previous round z-reads (h=1) done
    if (mh == h) {
      #pragma unroll
      for (int m = 0; m < 4; ++m) {
        #pragma unroll
        for (int q = 0; q < 2; ++q) {
          int oc = jj * 64 + (g0 + q) * 16 + l15;
          #pragma unroll
          for (int r = 0; r < 4; ++r) {
            int px = m * 16 + l4 * 4 + r;
            z_lds[px * ZP + oc] = acc[m][q][r];
          }
        }
      }
    }
    __syncthreads();
    // finish: thread -> (px = tid>>4, f4 = (tid&15)*4); 16 consecutive lanes
    // read 64 consecutive floats per gate row (coalesced LDS pattern).
    int px = tid >> 4;
    int f4 = (tid & 15) * 4;
    const float* zr = z_lds + px * ZP;
    float4 zi4 = *reinterpret_cast<const float4*>(zr + f4);
    float4 zf4 = *reinterpret_cast<const float4*>(zr + 64 + f4);
    float4 zc4 = *reinterpret_cast<const float4*>(zr + 128 + f4);
    float4 zo4 = *reinterpret_cast<const float4*>(zr + 192 + f4);
    float4 bi4 = *reinterpret_cast<const float4*>(bias + f4);
    float4 bf4 = *reinterpret_cast<const float4*>(bias + 64 + f4);
    float4 bc4 = *reinterpret_cast<const float4*>(bias + 128 + f4);
    float4 bo4 = *reinterpret_cast<const float4*>(bias + 192 + f4);
    int off0 = (pix_base + h * 64 + px) * 64 + f4;
    float4 co4 = *reinterpret_cast<const float4*>(c_old + off0);
    float4 hn4, cn4;
    #pragma unroll
    for (int e = 0; e < 4; ++e) {
      float zi = (&zi4.x)[e] + (&bi4.x)[e];
      float zf = (&zf4.x)[e] + (&bf4.x)[e];
      float zc = (&zc4.x)[e] + (&bc4.x)[e];
      float zo = (&zo4.x)[e] + (&bo4.x)[e];
      float ig = hsig(zi), fg = hsig(zf), og = hsig(zo);
      float cn = fg * (&co4.x)[e] + ig * tanhf(zc);
      (&cn4.x)[e] = cn;
      (&hn4.x)[e] = og * tanhf(cn);
    }
    *reinterpret_cast<float4*>(c_out + off0) = cn4;
    *reinterpret_cast<float4*>(h_out + off0) = hn4;
  }
}

// ---------------- 1x1 conv head ----------------
__global__ void frames_kernel(const float* __restrict__ h, const float* __restrict__ cw,
                              const float* __restrict__ cbp, float* __restrict__ out) {
  int tid = blockIdx.x * 256 + threadIdx.x;
  int p  = tid >> 2;
  int fc = (tid & 3) * 16;
  const float4* hp = reinterpret_cast<const float4*>(h + p * 64 + fc);
  const float4* wp = reinterpret_cast<const float4*>(cw + fc);
  float s = 0.0f;
  #pragma unroll
  for (int i = 0; i < 4; ++i) {
    float4 v = hp[i];
    float4 w = wp[i];
    s += v.x * w.x + v.y * w.y + v.z * w.z + v.w * w.w;
  }
  s += __shfl_xor(s, 1);
  s += __shfl_xor(s, 2);
  if ((tid & 3) == 0) out[p] = s + cbp[0];
}

// ---------------- launch ----------------
extern "C" void kernel_launch(void* const* d_in, const int* in_sizes, int n_in,
                              void* d_out, int out_size, void* d_ws, size_t ws_size,
                              hipStream_t stream) {
  const float* x   = (const float*)d_in[0];
  const float* h0  = (const float*)d_in[1];
  const float* c0  = (const float*)d_in[2];
  const float* h1  = (const float*)d_in[3];
  const float* c1  = (const float*)d_in[4];
  const float* k0  = (const float*)d_in[5];
  const float* rk0 = (const float*)d_in[6];
  const float* b0  = (const float*)d_in[7];
  const float* k1  = (const float*)d_in[8];
  const float* rk1 = (const float*)d_in[9];
  const float* b1  = (const float*)d_in[10];
  const float* cw  = (const float*)d_in[11];
  const float* cbp = (const float*)d_in[12];

  float* out    = (float*)d_out;
  float* frames = out;                       // [32,64,64,1]
  float* h0n    = out + 131072;              // [32,64,64,64]
  float* c0n    = out + 131072 + 8388608;
  float* h1n    = out + 131072 + 2 * 8388608;
  float* c1n    = out + 131072 + 3 * 8388608;

  char* ws = (char*)d_ws;
  const size_t SZ_H = 16777216;  // bytes per bf16 [32,64,64,64] buffer
  s16* h0nb = (s16*)(ws + 0 * SZ_H);
  s16* w0q  = (s16*)(ws + 1 * SZ_H);                 // rk0 shuffled
  s16* w1q  = (s16*)(ws + 1 * SZ_H + 1 * 294912);    // k1 shuffled
  s16* w2q  = (s16*)(ws + 1 * SZ_H + 2 * 294912);    // rk1 shuffled
  s16* k0t  = (s16*)(ws + 1 * SZ_H + 3 * 294912);    // k0 padded [256][32]

  // prep (single launch)
  wprep_kernel<<<1760, 256, 0, stream>>>(rk0, k1, rk1, k0, w0q, w1q, w2q, k0t);

  // layer 0 (R15 structure: measured best L0, ~42 us)
  cell0_kernel<<<512, 1024, 0, stream>>>(
      h0, w0q, x, k0t, b0, c0, h0n, c0n, h0nb);

  // layer 1 (W-in-registers, quarter-pass reloads)
  cell1_kernel<<<1024, 1024, 0, stream>>>(
      h0nb, h1, w1q, w2q, b1, c1, h1n, c1n);

  // head
  frames_kernel<<<2048, 256, 0, stream>>>(h1n, cw, cbp, frames);
}